// Round 3
// baseline (686.401 us; speedup 1.0000x reference)
//
#include <hip/hip_runtime.h>
#include <hip/hip_bf16.h>

#define DEVI __device__ __forceinline__

typedef short bf16x8 __attribute__((ext_vector_type(8)));
typedef float f32x4  __attribute__((ext_vector_type(4)));
typedef unsigned short u16;

using bf16 = __hip_bfloat16;

DEVI bf16x8 ld8(const bf16* p) { return *reinterpret_cast<const bf16x8*>(p); }

DEVI u16 f2bu(float f) {
  union { bf16 h; u16 u; } c; c.h = __float2bfloat16(f); return c.u;
}
DEVI float b2f(u16 u) {
  union { float f; unsigned int i; } c; c.i = ((unsigned int)u) << 16; return c.f;
}

DEVI void gload_lds16(const bf16* g, bf16* l) {
  typedef const __attribute__((address_space(1))) char* gp_t;
  typedef __attribute__((address_space(3))) char* lp_t;
  __builtin_amdgcn_global_load_lds((gp_t)(const void*)g, (lp_t)(void*)l, 16, 0, 0);
}

#define MFMA16(a, b, c) __builtin_amdgcn_mfma_f32_16x16x32_bf16((a), (b), (c), 0, 0, 0)

// Sizes: B=4, C=256, N=4096 (64x64), 3C=768, groups=32 (8 ch each)

// ---------------- K0: weights fp32 -> bf16 ----------------
__global__ __launch_bounds__(256) void wconv_kernel(const float* __restrict__ wq,
                                                    const float* __restrict__ wp,
                                                    bf16* __restrict__ wqb,
                                                    bf16* __restrict__ wpb) {
  int tid = blockIdx.x * 256 + threadIdx.x;
  const bool isq = tid < 49152;
  float4 v = isq ? ((const float4*)wq)[tid] : ((const float4*)wp)[tid - 49152];
  alignas(8) bf16 o[4] = { __float2bfloat16(v.x), __float2bfloat16(v.y),
                           __float2bfloat16(v.z), __float2bfloat16(v.w) };
  uint2 pk = *reinterpret_cast<uint2*>(o);
  if (isq) ((uint2*)wqb)[tid] = pk;
  else     ((uint2*)wpb)[tid - 49152] = pk;
}

// ---------------- K1: GroupNorm -> ht[b][n][c] bf16 ----------------
__global__ __launch_bounds__(256) void gn_kernel(const float* __restrict__ x,
                                                 const float* __restrict__ gw,
                                                 const float* __restrict__ gb,
                                                 bf16* __restrict__ ht) {
  const int blk = blockIdx.x;            // b*32 + g
  const int bb = blk >> 5, g = blk & 31;
  const float* xg = x + (size_t)(bb * 256 + g * 8) * 4096;

  float s = 0.f, ss = 0.f;
  const float4* x4 = (const float4*)xg;
  for (int i = threadIdx.x; i < 8192; i += 256) {
    float4 v = x4[i];
    s  += v.x + v.y + v.z + v.w;
    ss += v.x * v.x + v.y * v.y + v.z * v.z + v.w * v.w;
  }
  #pragma unroll
  for (int off = 32; off; off >>= 1) {
    s  += __shfl_down(s, off);
    ss += __shfl_down(ss, off);
  }
  __shared__ float red[8];
  int wave = threadIdx.x >> 6;
  if ((threadIdx.x & 63) == 0) { red[wave * 2] = s; red[wave * 2 + 1] = ss; }
  __syncthreads();
  if (threadIdx.x == 0) {
    float S = red[0] + red[2] + red[4] + red[6];
    float SS = red[1] + red[3] + red[5] + red[7];
    float mu = S * (1.f / 32768.f);
    float var = SS * (1.f / 32768.f) - mu * mu;
    red[0] = mu; red[1] = rsqrtf(var + 1e-5f);
  }
  __syncthreads();
  const float mu = red[0], rstd = red[1];

  float gm[8], bt[8];
  #pragma unroll
  for (int j = 0; j < 8; ++j) {
    float wv = gw[g * 8 + j] * rstd;
    gm[j] = wv; bt[j] = gb[g * 8 + j] - mu * wv;
  }
  bf16* hrow = ht + (size_t)bb * 4096 * 256 + g * 8;
  for (int n = threadIdx.x; n < 4096; n += 256) {
    alignas(16) u16 u[8];
    #pragma unroll
    for (int j = 0; j < 8; ++j)
      u[j] = f2bu(xg[j * 4096 + n] * gm[j] + bt[j]);
    *reinterpret_cast<uint4*>(hrow + (size_t)n * 256) = *reinterpret_cast<uint4*>(u);
  }
}

// ---------------- K2: QKV GEMM, qkvt[n][o] = ht[n][c]*W[o][c]^T + bias; Q pre-scaled 1/16 ----------------
__global__ __launch_bounds__(256) void qkv_gemm(const bf16* __restrict__ ht,
                                                const bf16* __restrict__ wq,
                                                const float* __restrict__ qkvb,
                                                bf16* __restrict__ qkvt) {
  int bid = blockIdx.x;
  int nt = bid & 31; int rest = bid >> 5;
  int bb = rest / 6; int ot = rest - bb * 6;
  int tid = threadIdx.x, lane = tid & 63, w = tid >> 6;
  int ln = lane & 15, hi = lane >> 4;
  int wr = w >> 1, wc = w & 1;
  int n_base = nt * 128 + wr * 64, o_base = ot * 128 + wc * 64;
  const bf16* hb = ht + (size_t)bb * 4096 * 256;

  f32x4 acc[4][4] = {};
  for (int cb = 0; cb < 8; ++cb) {
    int c0 = cb * 32 + hi * 8;
    bf16x8 af[4], bfr[4];
    #pragma unroll
    for (int i = 0; i < 4; ++i) af[i]  = ld8(hb + (size_t)(n_base + i * 16 + ln) * 256 + c0);
    #pragma unroll
    for (int j = 0; j < 4; ++j) bfr[j] = ld8(wq + (size_t)(o_base + j * 16 + ln) * 256 + c0);
    #pragma unroll
    for (int i = 0; i < 4; ++i)
      #pragma unroll
      for (int j = 0; j < 4; ++j)
        acc[i][j] = MFMA16(af[i], bfr[j], acc[i][j]);
  }

  const float sc = (ot < 2) ? 0.0625f : 1.0f;   // fold the 1/sqrt(C)=1/16 into Q
  bf16* ob = qkvt + (size_t)bb * 4096 * 768;
  #pragma unroll
  for (int j = 0; j < 4; ++j) {
    int o = o_base + j * 16 + ln;
    float bias = qkvb[o];
    #pragma unroll
    for (int i = 0; i < 4; ++i)
      #pragma unroll
      for (int r = 0; r < 4; ++r) {
        int n = n_base + i * 16 + hi * 4 + r;
        ob[(size_t)n * 768 + o] = __float2bfloat16((acc[i][j][r] + bias) * sc);
      }
  }
}

// ---------------- K3: transpose V -> vT[c][n] ----------------
__global__ __launch_bounds__(256) void vtrans_kernel(const bf16* __restrict__ qkvt,
                                                     bf16* __restrict__ vT) {
  int bid = blockIdx.x;
  int ct = bid & 3, ntile = (bid >> 2) & 63, bb = bid >> 8;
  __shared__ bf16 T[64][72];
  int tid = threadIdx.x;
  int i = tid >> 3, j8 = (tid & 7) * 8;
  const bf16* src = qkvt + (size_t)bb * 4096 * 768 + (size_t)(ntile * 64 + i) * 768 + 512 + ct * 64 + j8;
  #pragma unroll
  for (int p = 0; p < 2; ++p) {
    bf16x8 v = ld8(src + (size_t)p * 32 * 768);
    *reinterpret_cast<bf16x8*>(&T[i + p * 32][j8]) = v;
  }
  __syncthreads();
  bf16* dst = vT + (size_t)bb * 256 * 4096 + (size_t)(ct * 64) * 4096 + ntile * 64;
  #pragma unroll
  for (int p = 0; p < 2; ++p) {
    int c = i + p * 32;
    alignas(16) bf16 u[8];
    #pragma unroll
    for (int q = 0; q < 8; ++q) u[q] = T[j8 + q][c];
    *reinterpret_cast<uint4*>(dst + (size_t)c * 4096 + j8) = *reinterpret_cast<uint4*>(u);
  }
}

// ---------------- K4: flash attention, split-KV, LDS-staged K/V ----------------
// grid 512: L = bb(2b)|sp(2b)|qt(5b); 4 waves; wave owns 32 q-rows (block 128).
// K tile [64][256] + V^T tile [256][64] staged via global_load_lds w/ pre-swizzled
// source; reads XOR-deswizzle -> conflict-free ds_read_b128.
__global__ __launch_bounds__(256, 2) void attn_kernel(const bf16* __restrict__ qkvt,
                                                      const bf16* __restrict__ vT,
                                                      bf16* __restrict__ Opart,
                                                      float* __restrict__ ml) {
  int phys = blockIdx.x;
  int L = (phys & 7) * 64 + (phys >> 3);        // XCD chunk = 2 (bb,sp) K/V slices
  int bb = L >> 7, sp = (L >> 5) & 3, qt = L & 31;
  int tid = threadIdx.x, lane = tid & 63, w = tid >> 6;
  int ln = lane & 15, hi = lane >> 4;
  int n0 = qt * 128 + w * 32;
  const bf16* qb = qkvt + (size_t)bb * 4096 * 768;
  const bf16* vb = vT + (size_t)bb * 256 * 4096;

  __shared__ bf16 Kt[64 * 256];    // 32 KB, 16B-unit swizzle: col16 ^= (row&7)
  __shared__ bf16 Vt[256 * 64];    // 32 KB, same swizzle (row = channel)
  __shared__ bf16 Pl[4][32][64];   // 16 KB per-wave P tiles
  char* Plb = (char*)&Pl[w][0][0];
  const char* Kb = (const char*)Kt;
  const char* Vb = (const char*)Vt;

  // Q fragments in registers: 32 rows x 256 ch (Q pre-scaled by 1/16)
  bf16x8 aq[2][8];
  #pragma unroll
  for (int mt = 0; mt < 2; ++mt)
    #pragma unroll
    for (int cb = 0; cb < 8; ++cb)
      aq[mt][cb] = ld8(qb + (size_t)(n0 + mt * 16 + ln) * 768 + cb * 32 + hi * 8);

  f32x4 acc[2][16] = {};
  float m_run[2][4], lsum[2][4];
  #pragma unroll
  for (int mt = 0; mt < 2; ++mt)
    #pragma unroll
    for (int r = 0; r < 4; ++r) { m_run[mt][r] = -3.0e38f; lsum[mt][r] = 0.f; }

  for (int t = 0; t < 16; ++t) {
    int m0 = sp * 1024 + t * 64;

    // ---- stage K and V^T tiles into LDS (pre-swizzled global source) ----
    #pragma unroll
    for (int q = 0; q < 8; ++q) {
      int slot = w * 512 + q * 64 + lane;
      int kr = slot >> 5, kc = slot & 31;                       // K row / 16B-col
      const bf16* gk = qb + (size_t)(m0 + kr) * 768 + 256 + ((kc ^ (kr & 7)) << 3);
      gload_lds16(gk, Kt + (size_t)(w * 512 + q * 64) * 8);
      int vr = slot >> 3, vc = slot & 7;                        // V^T row(c) / 16B-col
      const bf16* gv = vb + (size_t)vr * 4096 + m0 + ((vc ^ (vr & 7)) << 3);
      gload_lds16(gv, Vt + (size_t)(w * 512 + q * 64) * 8);
    }
    __syncthreads();   // drains vmcnt -> tiles visible to all waves

    // ---- S = Q K^T (Q already has the 1/16 scale) ----
    f32x4 s[2][4] = {};
    __builtin_amdgcn_s_setprio(1);
    #pragma unroll
    for (int kt = 0; kt < 4; ++kt) {
      #pragma unroll
      for (int cb = 0; cb < 8; ++cb) {
        int krow = kt * 16 + ln;
        bf16x8 bk = *(const bf16x8*)(Kb + ((krow * 512 + cb * 64 + hi * 16) ^ ((krow & 7) << 4)));
        s[0][kt] = MFMA16(aq[0][cb], bk, s[0][kt]);
        s[1][kt] = MFMA16(aq[1][cb], bk, s[1][kt]);
      }
    }
    __builtin_amdgcn_s_setprio(0);

    // ---- tile row max (reduce over 16 lanes of the k-col dim) ----
    float mloc[2][4];
    #pragma unroll
    for (int mt = 0; mt < 2; ++mt)
      #pragma unroll
      for (int r = 0; r < 4; ++r) {
        float m = fmaxf(fmaxf(s[mt][0][r], s[mt][1][r]), fmaxf(s[mt][2][r], s[mt][3][r]));
        #pragma unroll
        for (int off = 1; off < 16; off <<= 1) m = fmaxf(m, __shfl_xor(m, off));
        mloc[mt][r] = m;
      }

    // ---- defer-max: rescale acc only when max grows by > 8 ----
    int need = 0;
    #pragma unroll
    for (int mt = 0; mt < 2; ++mt)
      #pragma unroll
      for (int r = 0; r < 4; ++r)
        need |= (mloc[mt][r] > m_run[mt][r] + 8.f) ? 1 : 0;
    if (__any(need)) {
      #pragma unroll
      for (int mt = 0; mt < 2; ++mt) {
        f32x4 al;
        #pragma unroll
        for (int r = 0; r < 4; ++r) {
          float mnew = fmaxf(m_run[mt][r], mloc[mt][r]);
          al[r] = __expf(m_run[mt][r] - mnew);
          m_run[mt][r] = mnew;
          lsum[mt][r] *= al[r];
        }
        #pragma unroll
        for (int cf = 0; cf < 16; ++cf) acc[mt][cf] = acc[mt][cf] * al;
      }
    }

    // ---- P = exp(S - m); per-lane partial l ----
    #pragma unroll
    for (int mt = 0; mt < 2; ++mt) {
      #pragma unroll
      for (int kt = 0; kt < 4; ++kt)
        #pragma unroll
        for (int r = 0; r < 4; ++r)
          s[mt][kt][r] = __expf(s[mt][kt][r] - m_run[mt][r]);
      #pragma unroll
      for (int r = 0; r < 4; ++r)
        lsum[mt][r] += s[mt][0][r] + s[mt][1][r] + s[mt][2][r] + s[mt][3][r];
    }

    // ---- P -> LDS (per-wave tile, swizzled; no barrier needed) ----
    #pragma unroll
    for (int mt = 0; mt < 2; ++mt)
      #pragma unroll
      for (int kt = 0; kt < 4; ++kt)
        #pragma unroll
        for (int r = 0; r < 4; ++r) {
          int row = mt * 16 + hi * 4 + r;
          int byte = (row * 128 + (kt * 16 + ln) * 2) ^ ((row & 7) << 4);
          *(bf16*)(Plb + byte) = __float2bfloat16(s[mt][kt][r]);
        }

    // ---- O += P V ----
    __builtin_amdgcn_s_setprio(1);
    #pragma unroll
    for (int ms = 0; ms < 2; ++ms) {
      int r0 = ln, r1 = 16 + ln;
      bf16x8 pa0 = *(const bf16x8*)(Plb + ((r0 * 128 + ms * 64 + hi * 16) ^ ((r0 & 7) << 4)));
      bf16x8 pa1 = *(const bf16x8*)(Plb + ((r1 * 128 + ms * 64 + hi * 16) ^ ((r1 & 7) << 4)));
      #pragma unroll
      for (int cf = 0; cf < 16; ++cf) {
        int vrow = cf * 16 + ln;
        bf16x8 bv = *(const bf16x8*)(Vb + ((vrow * 128 + ms * 64 + hi * 16) ^ ((vrow & 7) << 4)));
        acc[0][cf] = MFMA16(pa0, bv, acc[0][cf]);
        acc[1][cf] = MFMA16(pa1, bv, acc[1][cf]);
      }
    }
    __builtin_amdgcn_s_setprio(0);
    __syncthreads();   // all waves done reading K/V before next stage
  }

  // ---- epilogue: reduce l, write (m,l) + unnormalized partial O ----
  #pragma unroll
  for (int mt = 0; mt < 2; ++mt)
    #pragma unroll
    for (int r = 0; r < 4; ++r) {
      float v = lsum[mt][r];
      #pragma unroll
      for (int off = 1; off < 16; off <<= 1) v += __shfl_xor(v, off);
      lsum[mt][r] = v;
    }
  size_t rb = (size_t)sp * 16384 + (size_t)bb * 4096;
  if (ln == 0) {
    #pragma unroll
    for (int mt = 0; mt < 2; ++mt)
      #pragma unroll
      for (int r = 0; r < 4; ++r) {
        int n = n0 + mt * 16 + hi * 4 + r;
        ml[(rb + n) * 2]     = m_run[mt][r];
        ml[(rb + n) * 2 + 1] = lsum[mt][r];
      }
  }
  bf16* ob = Opart + rb * 256;
  #pragma unroll
  for (int mt = 0; mt < 2; ++mt)
    #pragma unroll
    for (int r = 0; r < 4; ++r) {
      int n = n0 + mt * 16 + hi * 4 + r;
      #pragma unroll
      for (int cf = 0; cf < 16; ++cf)
        ob[(size_t)n * 256 + cf * 16 + ln] = __float2bfloat16(acc[mt][cf][r]);
    }
}

// ---------------- K4b: combine split-KV partials -> ho[b][n][c] ----------------
__global__ __launch_bounds__(256) void combine_kernel(const bf16* __restrict__ Opart,
                                                      const float* __restrict__ ml,
                                                      bf16* __restrict__ ho) {
  int rowg = blockIdx.x * 32 + (threadIdx.x >> 3);   // b*4096 + n
  int cg = (threadIdx.x & 7) * 32;
  float msp[4]; float M = -3.0e38f;
  #pragma unroll
  for (int sp = 0; sp < 4; ++sp) {
    msp[sp] = ml[((size_t)sp * 16384 + rowg) * 2];
    M = fmaxf(M, msp[sp]);
  }
  float acc[32];
  #pragma unroll
  for (int j = 0; j < 32; ++j) acc[j] = 0.f;
  float Ltot = 0.f;
  #pragma unroll
  for (int sp = 0; sp < 4; ++sp) {
    float sc = __expf(msp[sp] - M);
    Ltot += ml[((size_t)sp * 16384 + rowg) * 2 + 1] * sc;
    const bf16* p = Opart + ((size_t)sp * 16384 + rowg) * 256 + cg;
    #pragma unroll
    for (int v = 0; v < 4; ++v) {
      bf16x8 u = ld8(p + v * 8);
      #pragma unroll
      for (int j = 0; j < 8; ++j) acc[v * 8 + j] += sc * b2f((u16)u[j]);
    }
  }
  float inv = 1.f / Ltot;
  bf16* o = ho + (size_t)rowg * 256 + cg;
  #pragma unroll
  for (int v = 0; v < 4; ++v) {
    alignas(16) u16 u[8];
    #pragma unroll
    for (int j = 0; j < 8; ++j) u[j] = f2bu(acc[v * 8 + j] * inv);
    *reinterpret_cast<uint4*>(o + v * 8) = *reinterpret_cast<uint4*>(u);
  }
}

// ---------------- K5: proj GEMM + residual ----------------
__global__ __launch_bounds__(256) void proj_gemm(const bf16* __restrict__ ho,
                                                 const bf16* __restrict__ wp,
                                                 const float* __restrict__ pb,
                                                 const float* __restrict__ x,
                                                 float* __restrict__ out) {
  int bid = blockIdx.x;
  int nt = bid & 31; int rest = bid >> 5;
  int ot = rest & 1; int bb = rest >> 1;
  int tid = threadIdx.x, lane = tid & 63, w = tid >> 6;
  int ln = lane & 15, hi = lane >> 4;
  int wr = w >> 1, wc = w & 1;
  int o_base = ot * 128 + wr * 64, n_base = nt * 128 + wc * 64;
  const bf16* hb = ho + (size_t)bb * 4096 * 256;

  f32x4 acc[4][4] = {};
  for (int cb = 0; cb < 8; ++cb) {
    int c0 = cb * 32 + hi * 8;
    bf16x8 af[4], bfr[4];
    #pragma unroll
    for (int i = 0; i < 4; ++i) af[i]  = ld8(wp + (size_t)(o_base + i * 16 + ln) * 256 + c0);
    #pragma unroll
    for (int j = 0; j < 4; ++j) bfr[j] = ld8(hb + (size_t)(n_base + j * 16 + ln) * 256 + c0);
    #pragma unroll
    for (int i = 0; i < 4; ++i)
      #pragma unroll
      for (int j = 0; j < 4; ++j)
        acc[i][j] = MFMA16(af[i], bfr[j], acc[i][j]);
  }

  const float* xb = x + (size_t)bb * 256 * 4096;
  float* ob = out + (size_t)bb * 256 * 4096;
  #pragma unroll
  for (int i = 0; i < 4; ++i)
    #pragma unroll
    for (int r = 0; r < 4; ++r) {
      int o = o_base + i * 16 + hi * 4 + r;
      float bias = pb[o];
      #pragma unroll
      for (int j = 0; j < 4; ++j) {
        int n = n_base + j * 16 + ln;
        size_t idx = (size_t)o * 4096 + n;
        ob[idx] = xb[idx] + bias + acc[i][j][r];
      }
    }
}

extern "C" void kernel_launch(void* const* d_in, const int* in_sizes, int n_in,
                              void* d_out, int out_size, void* d_ws, size_t ws_size,
                              hipStream_t stream) {
  const float* x   = (const float*)d_in[0];
  const float* gnw = (const float*)d_in[1];
  const float* gnb = (const float*)d_in[2];
  const float* qw  = (const float*)d_in[3];
  const float* qb  = (const float*)d_in[4];
  const float* pw  = (const float*)d_in[5];
  const float* pb  = (const float*)d_in[6];
  float* out = (float*)d_out;

  char* ws = (char*)d_ws;
  bf16* ht    = (bf16*)(ws);                               // [4][4096][256]    0..8 MB
  bf16* qkvt  = (bf16*)(ws + ((size_t)8 << 20));           // [4][4096][768]    8..32 MB
  bf16* vT    = (bf16*)(ws + ((size_t)32 << 20));          // [4][256][4096]   32..40 MB
  bf16* ho    = (bf16*)(ws + ((size_t)40 << 20));          // [4][4096][256]   40..48 MB
  bf16* wqb   = (bf16*)(ws + ((size_t)48 << 20));          // [768][256]
  bf16* wpb   = (bf16*)(ws + ((size_t)48 << 20) + 768 * 256 * 2);
  float* ml   = (float*)(ws + ((size_t)48 << 20) + ((size_t)1 << 19)); // [4][16384][2] f32
  bf16* Opart = (bf16*)(ws + ((size_t)49 << 20));          // [4][16384][256] bf16, 49..81 MB

  wconv_kernel<<<dim3(256), dim3(256), 0, stream>>>(qw, pw, wqb, wpb);
  gn_kernel<<<dim3(128), dim3(256), 0, stream>>>(x, gnw, gnb, ht);
  qkv_gemm<<<dim3(768), dim3(256), 0, stream>>>(ht, wqb, qb, qkvt);
  vtrans_kernel<<<dim3(1024), dim3(256), 0, stream>>>(qkvt, vT);
  attn_kernel<<<dim3(512), dim3(256), 0, stream>>>(qkvt, vT, Opart, ml);
  combine_kernel<<<dim3(512), dim3(256), 0, stream>>>(Opart, ml, ho);
  proj_gemm<<<dim3(256), dim3(256), 0, stream>>>(ho, wpb, pb, x, out);
}

// Round 4
// 338.815 us; speedup vs baseline: 2.0259x; 2.0259x over previous
//
#include <hip/hip_runtime.h>
#include <hip/hip_bf16.h>

#define DEVI __device__ __forceinline__

typedef short bf16x8 __attribute__((ext_vector_type(8)));
typedef float f32x4  __attribute__((ext_vector_type(4)));
typedef float f32x16 __attribute__((ext_vector_type(16)));
typedef unsigned short u16;
typedef unsigned int u32;

using bf16 = __hip_bfloat16;

DEVI bf16x8 ld8(const bf16* p) { return *reinterpret_cast<const bf16x8*>(p); }

DEVI u16 f2bu(float f) {
  union { bf16 h; u16 u; } c; c.h = __float2bfloat16(f); return c.u;
}
DEVI float b2f(u16 u) {
  union { float f; unsigned int i; } c; c.i = ((unsigned int)u) << 16; return c.f;
}

DEVI void gload_lds16(const bf16* g, bf16* l) {
  typedef const __attribute__((address_space(1))) char* gp_t;
  typedef __attribute__((address_space(3))) char* lp_t;
  __builtin_amdgcn_global_load_lds((gp_t)(const void*)g, (lp_t)(void*)l, 16, 0, 0);
}

#define MFMA16(a, b, c) __builtin_amdgcn_mfma_f32_16x16x32_bf16((a), (b), (c), 0, 0, 0)
#define MFMA32(a, b, c) __builtin_amdgcn_mfma_f32_32x32x16_bf16((a), (b), (c), 0, 0, 0)

// Sizes: B=4, C=256, N=4096 (64x64), 3C=768, groups=32 (8 ch each)

// ---------------- K0: weights fp32 -> bf16 ----------------
__global__ __launch_bounds__(256) void wconv_kernel(const float* __restrict__ wq,
                                                    const float* __restrict__ wp,
                                                    bf16* __restrict__ wqb,
                                                    bf16* __restrict__ wpb) {
  int tid = blockIdx.x * 256 + threadIdx.x;
  const bool isq = tid < 49152;
  float4 v = isq ? ((const float4*)wq)[tid] : ((const float4*)wp)[tid - 49152];
  alignas(8) bf16 o[4] = { __float2bfloat16(v.x), __float2bfloat16(v.y),
                           __float2bfloat16(v.z), __float2bfloat16(v.w) };
  uint2 pk = *reinterpret_cast<uint2*>(o);
  if (isq) ((uint2*)wqb)[tid] = pk;
  else     ((uint2*)wpb)[tid - 49152] = pk;
}

// ---------------- K1: GroupNorm -> ht[b][n][c] bf16 ----------------
__global__ __launch_bounds__(256) void gn_kernel(const float* __restrict__ x,
                                                 const float* __restrict__ gw,
                                                 const float* __restrict__ gb,
                                                 bf16* __restrict__ ht) {
  const int blk = blockIdx.x;            // b*32 + g
  const int bb = blk >> 5, g = blk & 31;
  const float* xg = x + (size_t)(bb * 256 + g * 8) * 4096;

  float s = 0.f, ss = 0.f;
  const float4* x4 = (const float4*)xg;
  for (int i = threadIdx.x; i < 8192; i += 256) {
    float4 v = x4[i];
    s  += v.x + v.y + v.z + v.w;
    ss += v.x * v.x + v.y * v.y + v.z * v.z + v.w * v.w;
  }
  #pragma unroll
  for (int off = 32; off; off >>= 1) {
    s  += __shfl_down(s, off);
    ss += __shfl_down(ss, off);
  }
  __shared__ float red[8];
  int wave = threadIdx.x >> 6;
  if ((threadIdx.x & 63) == 0) { red[wave * 2] = s; red[wave * 2 + 1] = ss; }
  __syncthreads();
  if (threadIdx.x == 0) {
    float S = red[0] + red[2] + red[4] + red[6];
    float SS = red[1] + red[3] + red[5] + red[7];
    float mu = S * (1.f / 32768.f);
    float var = SS * (1.f / 32768.f) - mu * mu;
    red[0] = mu; red[1] = rsqrtf(var + 1e-5f);
  }
  __syncthreads();
  const float mu = red[0], rstd = red[1];

  float gm[8], bt[8];
  #pragma unroll
  for (int j = 0; j < 8; ++j) {
    float wv = gw[g * 8 + j] * rstd;
    gm[j] = wv; bt[j] = gb[g * 8 + j] - mu * wv;
  }
  bf16* hrow = ht + (size_t)bb * 4096 * 256 + g * 8;
  for (int n = threadIdx.x; n < 4096; n += 256) {
    alignas(16) u16 u[8];
    #pragma unroll
    for (int j = 0; j < 8; ++j)
      u[j] = f2bu(xg[j * 4096 + n] * gm[j] + bt[j]);
    *reinterpret_cast<uint4*>(hrow + (size_t)n * 256) = *reinterpret_cast<uint4*>(u);
  }
}

// ---------------- K2: QKV GEMM, qkvt[n][o] = ht[n][c]*W[o][c]^T + bias; Q pre-scaled 1/16 ----------------
__global__ __launch_bounds__(256) void qkv_gemm(const bf16* __restrict__ ht,
                                                const bf16* __restrict__ wq,
                                                const float* __restrict__ qkvb,
                                                bf16* __restrict__ qkvt) {
  int bid = blockIdx.x;
  int nt = bid & 31; int rest = bid >> 5;
  int bb = rest / 6; int ot = rest - bb * 6;
  int tid = threadIdx.x, lane = tid & 63, w = tid >> 6;
  int ln = lane & 15, hi = lane >> 4;
  int wr = w >> 1, wc = w & 1;
  int n_base = nt * 128 + wr * 64, o_base = ot * 128 + wc * 64;
  const bf16* hb = ht + (size_t)bb * 4096 * 256;

  f32x4 acc[4][4] = {};
  for (int cb = 0; cb < 8; ++cb) {
    int c0 = cb * 32 + hi * 8;
    bf16x8 af[4], bfr[4];
    #pragma unroll
    for (int i = 0; i < 4; ++i) af[i]  = ld8(hb + (size_t)(n_base + i * 16 + ln) * 256 + c0);
    #pragma unroll
    for (int j = 0; j < 4; ++j) bfr[j] = ld8(wq + (size_t)(o_base + j * 16 + ln) * 256 + c0);
    #pragma unroll
    for (int i = 0; i < 4; ++i)
      #pragma unroll
      for (int j = 0; j < 4; ++j)
        acc[i][j] = MFMA16(af[i], bfr[j], acc[i][j]);
  }

  const float sc = (ot < 2) ? 0.0625f : 1.0f;   // fold the 1/sqrt(C)=1/16 into Q
  bf16* ob = qkvt + (size_t)bb * 4096 * 768;
  #pragma unroll
  for (int j = 0; j < 4; ++j) {
    int o = o_base + j * 16 + ln;
    float bias = qkvb[o];
    #pragma unroll
    for (int i = 0; i < 4; ++i)
      #pragma unroll
      for (int r = 0; r < 4; ++r) {
        int n = n_base + i * 16 + hi * 4 + r;
        ob[(size_t)n * 768 + o] = __float2bfloat16((acc[i][j][r] + bias) * sc);
      }
  }
}

// ---------------- K3: transpose V -> vT[c][n] ----------------
__global__ __launch_bounds__(256) void vtrans_kernel(const bf16* __restrict__ qkvt,
                                                     bf16* __restrict__ vT) {
  int bid = blockIdx.x;
  int ct = bid & 3, ntile = (bid >> 2) & 63, bb = bid >> 8;
  __shared__ bf16 T[64][72];
  int tid = threadIdx.x;
  int i = tid >> 3, j8 = (tid & 7) * 8;
  const bf16* src = qkvt + (size_t)bb * 4096 * 768 + (size_t)(ntile * 64 + i) * 768 + 512 + ct * 64 + j8;
  #pragma unroll
  for (int p = 0; p < 2; ++p) {
    bf16x8 v = ld8(src + (size_t)p * 32 * 768);
    *reinterpret_cast<bf16x8*>(&T[i + p * 32][j8]) = v;
  }
  __syncthreads();
  bf16* dst = vT + (size_t)bb * 256 * 4096 + (size_t)(ct * 64) * 4096 + ntile * 64;
  #pragma unroll
  for (int p = 0; p < 2; ++p) {
    int c = i + p * 32;
    alignas(16) bf16 u[8];
    #pragma unroll
    for (int q = 0; q < 8; ++q) u[q] = T[j8 + q][c];
    *reinterpret_cast<uint4*>(dst + (size_t)c * 4096 + j8) = *reinterpret_cast<uint4*>(u);
  }
}

// ---------------- K4: flash attention, 32x32 MFMA, swapped QK^T, in-register P ----------------
// grid 256, 512 threads (8 waves x 32 q-rows = 256 q-rows/block).
// K tile [64][256] (32KB) + V^T tile [256][64] (32KB), double-buffered = 128KB LDS.
// XCD-aligned: each XCD hosts exactly 2 (bb,sp) KV slices (2MB).
__global__ __launch_bounds__(512, 2) void attn_kernel(const bf16* __restrict__ qkvt,
                                                      const bf16* __restrict__ vT,
                                                      bf16* __restrict__ Opart,
                                                      float* __restrict__ ml) {
  const int phys = blockIdx.x;
  const int x = phys & 7, c = phys >> 3;          // XCD, chunk-local
  const int gs = x * 2 + (c >> 4);                // global slice = bb*4+sp
  const int qt = c & 15;
  const int bb = gs >> 2, sp = gs & 3;

  const int tid = threadIdx.x, lane = tid & 63, w = tid >> 6;
  const int ln32 = lane & 31, h = lane >> 5;
  const bool h0 = (h == 0);
  const int n0w = qt * 256 + w * 32;

  const bf16* qb = qkvt + (size_t)bb * 4096 * 768;
  const bf16* vb = vT + (size_t)bb * 256 * 4096;

  __shared__ bf16 KT[2][64 * 256];   // row=kv(64), 32 granules/row, swz: g ^= (row&31)
  __shared__ bf16 VT2[2][256 * 64];  // row=c(256), 8 granules/row,  swz: g ^= (row&7)

  // Q fragments (B-operand of S^T mfma): 32 q-rows x 256 ch, 16 ch-steps
  bf16x8 aq[16];
  #pragma unroll
  for (int step = 0; step < 16; ++step)
    aq[step] = ld8(qb + (size_t)(n0w + ln32) * 768 + step * 16 + h * 8);

  f32x16 acc[8] = {};
  float m_run = -3.0e38f, lsum = 0.f;

  // ---- prologue: stage tile 0 ----
  {
    int m0 = sp * 1024;
    #pragma unroll
    for (int i = 0; i < 4; ++i) {
      int G = i * 512 + tid;
      int kr = G >> 5, kc = G & 31;
      gload_lds16(qb + (size_t)(m0 + kr) * 768 + 256 + ((kc ^ (kr & 31)) << 3), KT[0] + (size_t)G * 8);
      int vr = G >> 3, vc = G & 7;
      gload_lds16(vb + (size_t)vr * 4096 + m0 + ((vc ^ (vr & 7)) << 3), VT2[0] + (size_t)G * 8);
    }
  }
  __syncthreads();

  int cur = 0;
  for (int t = 0; t < 16; ++t) {
    // ---- issue stage of next tile (overlaps with this tile's compute) ----
    if (t < 15) {
      int m0n = sp * 1024 + (t + 1) * 64;
      #pragma unroll
      for (int i = 0; i < 4; ++i) {
        int G = i * 512 + tid;
        int kr = G >> 5, kc = G & 31;
        gload_lds16(qb + (size_t)(m0n + kr) * 768 + 256 + ((kc ^ (kr & 31)) << 3), KT[cur ^ 1] + (size_t)G * 8);
        int vr = G >> 3, vc = G & 7;
        gload_lds16(vb + (size_t)vr * 4096 + m0n + ((vc ^ (vr & 7)) << 3), VT2[cur ^ 1] + (size_t)G * 8);
      }
    }

    const char* Kb = (const char*)KT[cur];
    const char* Vb = (const char*)VT2[cur];

    // ---- S^T = K . Q^T : lane holds P-row q=ln32, kv = 32g + (r&3)+8*(r>>2)+4h ----
    f32x16 s0 = {}, s1 = {};
    __builtin_amdgcn_s_setprio(1);
    #pragma unroll
    for (int step = 0; step < 16; ++step) {
      int r0 = ln32, r1 = 32 + ln32;
      bf16x8 k0 = *(const bf16x8*)(Kb + r0 * 512 + (((step * 2 + h) ^ (r0 & 31)) << 4));
      bf16x8 k1 = *(const bf16x8*)(Kb + r1 * 512 + (((step * 2 + h) ^ (r1 & 31)) << 4));
      s0 = MFMA32(k0, aq[step], s0);
      s1 = MFMA32(k1, aq[step], s1);
    }
    __builtin_amdgcn_s_setprio(0);

    // ---- row max (q=ln32 lives at lanes {ln32, ln32+32}) ----
    float mx = -3.0e38f;
    #pragma unroll
    for (int r = 0; r < 16; ++r) { mx = fmaxf(mx, s0[r]); mx = fmaxf(mx, s1[r]); }
    mx = fmaxf(mx, __shfl_xor(mx, 32));

    // ---- defer-max rescale ----
    if (__any(mx > m_run + 8.f)) {
      float mnew = fmaxf(m_run, mx);
      float alpha = __expf(m_run - mnew);
      m_run = mnew;
      lsum *= alpha;
      #pragma unroll
      for (int r = 0; r < 16; ++r) {
        int qacc = (r & 3) + 8 * (r >> 2) + 4 * h;
        float ar = __shfl(alpha, qacc);
        #pragma unroll
        for (int ct = 0; ct < 8; ++ct) acc[ct][r] *= ar;
      }
    }

    // ---- P = exp(S - m); packs; cross-half swap ----
    u32 pk0[8], pk1[8], sw0[8], sw1[8];
    #pragma unroll
    for (int m = 0; m < 8; ++m) {
      float a0 = __expf(s0[2 * m] - m_run), b0 = __expf(s0[2 * m + 1] - m_run);
      float a1 = __expf(s1[2 * m] - m_run), b1 = __expf(s1[2 * m + 1] - m_run);
      lsum += a0 + b0 + a1 + b1;
      pk0[m] = ((u32)f2bu(b0) << 16) | f2bu(a0);
      pk1[m] = ((u32)f2bu(b1) << 16) | f2bu(a1);
    }
    #pragma unroll
    for (int m = 0; m < 8; ++m) {
      sw0[m] = __shfl_xor(pk0[m], 32);
      sw1[m] = __shfl_xor(pk1[m], 32);
    }

    // ---- O += P V : A-frag rebuilt in-register per 16-kv step ----
    __builtin_amdgcn_s_setprio(1);
    #pragma unroll
    for (int st = 0; st < 4; ++st) {
      const u32* P = (st >> 1) ? pk1 : pk0;
      const u32* S = (st >> 1) ? sw1 : sw0;
      const int A0 = 4 * (st & 1), A1 = A0 + 2;
      union { bf16x8 v; u32 u[4]; } af;
      af.u[0] = h0 ? P[A0]     : S[A1];
      af.u[1] = h0 ? P[A0 + 1] : S[A1 + 1];
      af.u[2] = h0 ? S[A0]     : P[A1];
      af.u[3] = h0 ? S[A0 + 1] : P[A1 + 1];
      #pragma unroll
      for (int ct = 0; ct < 8; ++ct) {
        int vrow = ct * 32 + ln32;
        bf16x8 bv = *(const bf16x8*)(Vb + vrow * 128 + (((st * 2 + h) ^ (vrow & 7)) << 4));
        acc[ct] = MFMA32(af.v, bv, acc[ct]);
      }
    }
    __builtin_amdgcn_s_setprio(0);

    __syncthreads();   // drains vmcnt/lgkm: publishes next tile, protects cur tile
    cur ^= 1;
  }

  // ---- epilogue ----
  float Lrow = lsum + __shfl_xor(lsum, 32);
  size_t rb = (size_t)sp * 16384 + (size_t)bb * 4096;
  if (lane < 32) {
    ml[(rb + n0w + lane) * 2]     = m_run;
    ml[(rb + n0w + lane) * 2 + 1] = Lrow;
  }
  bf16* ob = Opart + rb * 256;
  #pragma unroll
  for (int r = 0; r < 16; ++r) {
    int qacc = (r & 3) + 8 * (r >> 2) + 4 * h;
    int n = n0w + qacc;
    #pragma unroll
    for (int ct = 0; ct < 8; ++ct)
      ob[(size_t)n * 256 + ct * 32 + ln32] = __float2bfloat16(acc[ct][r]);
  }
}

// ---------------- K4b: combine split-KV partials -> ho[b][n][c] ----------------
__global__ __launch_bounds__(256) void combine_kernel(const bf16* __restrict__ Opart,
                                                      const float* __restrict__ ml,
                                                      bf16* __restrict__ ho) {
  int rowg = blockIdx.x * 32 + (threadIdx.x >> 3);   // b*4096 + n
  int cg = (threadIdx.x & 7) * 32;
  float msp[4]; float M = -3.0e38f;
  #pragma unroll
  for (int sp = 0; sp < 4; ++sp) {
    msp[sp] = ml[((size_t)sp * 16384 + rowg) * 2];
    M = fmaxf(M, msp[sp]);
  }
  float acc[32];
  #pragma unroll
  for (int j = 0; j < 32; ++j) acc[j] = 0.f;
  float Ltot = 0.f;
  #pragma unroll
  for (int sp = 0; sp < 4; ++sp) {
    float sc = __expf(msp[sp] - M);
    Ltot += ml[((size_t)sp * 16384 + rowg) * 2 + 1] * sc;
    const bf16* p = Opart + ((size_t)sp * 16384 + rowg) * 256 + cg;
    #pragma unroll
    for (int v = 0; v < 4; ++v) {
      bf16x8 u = ld8(p + v * 8);
      #pragma unroll
      for (int j = 0; j < 8; ++j) acc[v * 8 + j] += sc * b2f((u16)u[j]);
    }
  }
  float inv = 1.f / Ltot;
  bf16* o = ho + (size_t)rowg * 256 + cg;
  #pragma unroll
  for (int v = 0; v < 4; ++v) {
    alignas(16) u16 u[8];
    #pragma unroll
    for (int j = 0; j < 8; ++j) u[j] = f2bu(acc[v * 8 + j] * inv);
    *reinterpret_cast<uint4*>(o + v * 8) = *reinterpret_cast<uint4*>(u);
  }
}

// ---------------- K5: proj GEMM + residual ----------------
__global__ __launch_bounds__(256) void proj_gemm(const bf16* __restrict__ ho,
                                                 const bf16* __restrict__ wp,
                                                 const float* __restrict__ pb,
                                                 const float* __restrict__ x,
                                                 float* __restrict__ out) {
  int bid = blockIdx.x;
  int nt = bid & 31; int rest = bid >> 5;
  int ot = rest & 1; int bb = rest >> 1;
  int tid = threadIdx.x, lane = tid & 63, w = tid >> 6;
  int ln = lane & 15, hi = lane >> 4;
  int wr = w >> 1, wc = w & 1;
  int o_base = ot * 128 + wr * 64, n_base = nt * 128 + wc * 64;
  const bf16* hb = ho + (size_t)bb * 4096 * 256;

  f32x4 acc[4][4] = {};
  for (int cb = 0; cb < 8; ++cb) {
    int c0 = cb * 32 + hi * 8;
    bf16x8 af[4], bfr[4];
    #pragma unroll
    for (int i = 0; i < 4; ++i) af[i]  = ld8(wp + (size_t)(o_base + i * 16 + ln) * 256 + c0);
    #pragma unroll
    for (int j = 0; j < 4; ++j) bfr[j] = ld8(hb + (size_t)(n_base + j * 16 + ln) * 256 + c0);
    #pragma unroll
    for (int i = 0; i < 4; ++i)
      #pragma unroll
      for (int j = 0; j < 4; ++j)
        acc[i][j] = MFMA16(af[i], bfr[j], acc[i][j]);
  }

  const float* xb = x + (size_t)bb * 256 * 4096;
  float* ob = out + (size_t)bb * 256 * 4096;
  #pragma unroll
  for (int i = 0; i < 4; ++i)
    #pragma unroll
    for (int r = 0; r < 4; ++r) {
      int o = o_base + i * 16 + hi * 4 + r;
      float bias = pb[o];
      #pragma unroll
      for (int j = 0; j < 4; ++j) {
        int n = n_base + j * 16 + ln;
        size_t idx = (size_t)o * 4096 + n;
        ob[idx] = xb[idx] + bias + acc[i][j][r];
      }
    }
}

extern "C" void kernel_launch(void* const* d_in, const int* in_sizes, int n_in,
                              void* d_out, int out_size, void* d_ws, size_t ws_size,
                              hipStream_t stream) {
  const float* x   = (const float*)d_in[0];
  const float* gnw = (const float*)d_in[1];
  const float* gnb = (const float*)d_in[2];
  const float* qw  = (const float*)d_in[3];
  const float* qb  = (const float*)d_in[4];
  const float* pw  = (const float*)d_in[5];
  const float* pb  = (const float*)d_in[6];
  float* out = (float*)d_out;

  char* ws = (char*)d_ws;
  bf16* ht    = (bf16*)(ws);                               // [4][4096][256]    0..8 MB
  bf16* qkvt  = (bf16*)(ws + ((size_t)8 << 20));           // [4][4096][768]    8..32 MB
  bf16* vT    = (bf16*)(ws + ((size_t)32 << 20));          // [4][256][4096]   32..40 MB
  bf16* ho    = (bf16*)(ws + ((size_t)40 << 20));          // [4][4096][256]   40..48 MB
  bf16* wqb   = (bf16*)(ws + ((size_t)48 << 20));          // [768][256]
  bf16* wpb   = (bf16*)(ws + ((size_t)48 << 20) + 768 * 256 * 2);
  float* ml   = (float*)(ws + ((size_t)48 << 20) + ((size_t)1 << 19)); // [4][16384][2] f32
  bf16* Opart = (bf16*)(ws + ((size_t)49 << 20));          // [4][16384][256] bf16, 49..81 MB

  wconv_kernel<<<dim3(256), dim3(256), 0, stream>>>(qw, pw, wqb, wpb);
  gn_kernel<<<dim3(128), dim3(256), 0, stream>>>(x, gnw, gnb, ht);
  qkv_gemm<<<dim3(768), dim3(256), 0, stream>>>(ht, wqb, qb, qkvt);
  vtrans_kernel<<<dim3(1024), dim3(256), 0, stream>>>(qkvt, vT);
  attn_kernel<<<dim3(256), dim3(512), 0, stream>>>(qkvt, vT, Opart, ml);
  combine_kernel<<<dim3(512), dim3(256), 0, stream>>>(Opart, ml, ho);
  proj_gemm<<<dim3(256), dim3(256), 0, stream>>>(ho, wpb, pb, x, out);
}

// Round 5
// 272.536 us; speedup vs baseline: 2.5186x; 1.2432x over previous
//
#include <hip/hip_runtime.h>
#include <hip/hip_bf16.h>

#define DEVI __device__ __forceinline__

typedef short bf16x8 __attribute__((ext_vector_type(8)));
typedef float f32x4  __attribute__((ext_vector_type(4)));
typedef float f32x16 __attribute__((ext_vector_type(16)));
typedef unsigned short u16;
typedef unsigned int u32;

using bf16 = __hip_bfloat16;

DEVI bf16x8 ld8(const bf16* p) { return *reinterpret_cast<const bf16x8*>(p); }

DEVI u16 f2bu(float f) {
  union { bf16 h; u16 u; } c; c.h = __float2bfloat16(f); return c.u;
}
DEVI float b2f(u16 u) {
  union { float f; unsigned int i; } c; c.i = ((unsigned int)u) << 16; return c.f;
}

DEVI void gload_lds16(const bf16* g, bf16* l) {
  typedef const __attribute__((address_space(1))) char* gp_t;
  typedef __attribute__((address_space(3))) char* lp_t;
  __builtin_amdgcn_global_load_lds((gp_t)(const void*)g, (lp_t)(void*)l, 16, 0, 0);
}

#define MFMA16(a, b, c) __builtin_amdgcn_mfma_f32_16x16x32_bf16((a), (b), (c), 0, 0, 0)
#define MFMA32(a, b, c) __builtin_amdgcn_mfma_f32_32x32x16_bf16((a), (b), (c), 0, 0, 0)

// Sizes: B=4, C=256, N=4096 (64x64), 3C=768, groups=32 (8 ch each)

// ---------------- K0: weights fp32 -> bf16 ----------------
__global__ __launch_bounds__(256) void wconv_kernel(const float* __restrict__ wq,
                                                    const float* __restrict__ wp,
                                                    bf16* __restrict__ wqb,
                                                    bf16* __restrict__ wpb) {
  int tid = blockIdx.x * 256 + threadIdx.x;
  const bool isq = tid < 49152;
  float4 v = isq ? ((const float4*)wq)[tid] : ((const float4*)wp)[tid - 49152];
  alignas(8) bf16 o[4] = { __float2bfloat16(v.x), __float2bfloat16(v.y),
                           __float2bfloat16(v.z), __float2bfloat16(v.w) };
  uint2 pk = *reinterpret_cast<uint2*>(o);
  if (isq) ((uint2*)wqb)[tid] = pk;
  else     ((uint2*)wpb)[tid - 49152] = pk;
}

// ---------------- K1: GroupNorm -> ht[b][n][c] bf16 ----------------
__global__ __launch_bounds__(256) void gn_kernel(const float* __restrict__ x,
                                                 const float* __restrict__ gw,
                                                 const float* __restrict__ gb,
                                                 bf16* __restrict__ ht) {
  const int blk = blockIdx.x;            // b*32 + g
  const int bb = blk >> 5, g = blk & 31;
  const float* xg = x + (size_t)(bb * 256 + g * 8) * 4096;

  float s = 0.f, ss = 0.f;
  const float4* x4 = (const float4*)xg;
  for (int i = threadIdx.x; i < 8192; i += 256) {
    float4 v = x4[i];
    s  += v.x + v.y + v.z + v.w;
    ss += v.x * v.x + v.y * v.y + v.z * v.z + v.w * v.w;
  }
  #pragma unroll
  for (int off = 32; off; off >>= 1) {
    s  += __shfl_down(s, off);
    ss += __shfl_down(ss, off);
  }
  __shared__ float red[8];
  int wave = threadIdx.x >> 6;
  if ((threadIdx.x & 63) == 0) { red[wave * 2] = s; red[wave * 2 + 1] = ss; }
  __syncthreads();
  if (threadIdx.x == 0) {
    float S = red[0] + red[2] + red[4] + red[6];
    float SS = red[1] + red[3] + red[5] + red[7];
    float mu = S * (1.f / 32768.f);
    float var = SS * (1.f / 32768.f) - mu * mu;
    red[0] = mu; red[1] = rsqrtf(var + 1e-5f);
  }
  __syncthreads();
  const float mu = red[0], rstd = red[1];

  float gm[8], bt[8];
  #pragma unroll
  for (int j = 0; j < 8; ++j) {
    float wv = gw[g * 8 + j] * rstd;
    gm[j] = wv; bt[j] = gb[g * 8 + j] - mu * wv;
  }
  bf16* hrow = ht + (size_t)bb * 4096 * 256 + g * 8;
  for (int n = threadIdx.x; n < 4096; n += 256) {
    alignas(16) u16 u[8];
    #pragma unroll
    for (int j = 0; j < 8; ++j)
      u[j] = f2bu(xg[j * 4096 + n] * gm[j] + bt[j]);
    *reinterpret_cast<uint4*>(hrow + (size_t)n * 256) = *reinterpret_cast<uint4*>(u);
  }
}

// ---------------- K2: QKV GEMM, qkvt[n][o] = ht[n][c]*W[o][c]^T + bias; Q pre-scaled 1/16 ----------------
__global__ __launch_bounds__(256) void qkv_gemm(const bf16* __restrict__ ht,
                                                const bf16* __restrict__ wq,
                                                const float* __restrict__ qkvb,
                                                bf16* __restrict__ qkvt) {
  int bid = blockIdx.x;
  int nt = bid & 31; int rest = bid >> 5;
  int bb = rest / 6; int ot = rest - bb * 6;
  int tid = threadIdx.x, lane = tid & 63, w = tid >> 6;
  int ln = lane & 15, hi = lane >> 4;
  int wr = w >> 1, wc = w & 1;
  int n_base = nt * 128 + wr * 64, o_base = ot * 128 + wc * 64;
  const bf16* hb = ht + (size_t)bb * 4096 * 256;

  f32x4 acc[4][4] = {};
  for (int cb = 0; cb < 8; ++cb) {
    int c0 = cb * 32 + hi * 8;
    bf16x8 af[4], bfr[4];
    #pragma unroll
    for (int i = 0; i < 4; ++i) af[i]  = ld8(hb + (size_t)(n_base + i * 16 + ln) * 256 + c0);
    #pragma unroll
    for (int j = 0; j < 4; ++j) bfr[j] = ld8(wq + (size_t)(o_base + j * 16 + ln) * 256 + c0);
    #pragma unroll
    for (int i = 0; i < 4; ++i)
      #pragma unroll
      for (int j = 0; j < 4; ++j)
        acc[i][j] = MFMA16(af[i], bfr[j], acc[i][j]);
  }

  const float sc = (ot < 2) ? 0.0625f : 1.0f;   // fold the 1/sqrt(C)=1/16 into Q
  bf16* ob = qkvt + (size_t)bb * 4096 * 768;
  #pragma unroll
  for (int j = 0; j < 4; ++j) {
    int o = o_base + j * 16 + ln;
    float bias = qkvb[o];
    #pragma unroll
    for (int i = 0; i < 4; ++i)
      #pragma unroll
      for (int r = 0; r < 4; ++r) {
        int n = n_base + i * 16 + hi * 4 + r;
        ob[(size_t)n * 768 + o] = __float2bfloat16((acc[i][j][r] + bias) * sc);
      }
  }
}

// ---------------- K3: transpose V -> vT[c][n] ----------------
__global__ __launch_bounds__(256) void vtrans_kernel(const bf16* __restrict__ qkvt,
                                                     bf16* __restrict__ vT) {
  int bid = blockIdx.x;
  int ct = bid & 3, ntile = (bid >> 2) & 63, bb = bid >> 8;
  __shared__ bf16 T[64][72];
  int tid = threadIdx.x;
  int i = tid >> 3, j8 = (tid & 7) * 8;
  const bf16* src = qkvt + (size_t)bb * 4096 * 768 + (size_t)(ntile * 64 + i) * 768 + 512 + ct * 64 + j8;
  #pragma unroll
  for (int p = 0; p < 2; ++p) {
    bf16x8 v = ld8(src + (size_t)p * 32 * 768);
    *reinterpret_cast<bf16x8*>(&T[i + p * 32][j8]) = v;
  }
  __syncthreads();
  bf16* dst = vT + (size_t)bb * 256 * 4096 + (size_t)(ct * 64) * 4096 + ntile * 64;
  #pragma unroll
  for (int p = 0; p < 2; ++p) {
    int c = i + p * 32;
    alignas(16) bf16 u[8];
    #pragma unroll
    for (int q = 0; q < 8; ++q) u[q] = T[j8 + q][c];
    *reinterpret_cast<uint4*>(dst + (size_t)c * 4096 + j8) = *reinterpret_cast<uint4*>(u);
  }
}

// ---------------- K4: flash attention, 32x32 MFMA, swapped QK^T, in-register P ----------------
// grid 512, 256 threads (4 waves x 32 q-rows = 128 q-rows/block), 2 blocks/CU.
// KV tile 32: K[32][256] (16KB) + V^T[256][32] (16KB), double-buffered = 64KB LDS.
// XCD-aligned: each XCD hosts exactly 2 (bb,sp) KV slices (2MB < 4MB L2).
__global__ __launch_bounds__(256, 2) void attn_kernel(const bf16* __restrict__ qkvt,
                                                      const bf16* __restrict__ vT,
                                                      bf16* __restrict__ Opart,
                                                      float* __restrict__ ml) {
  const int phys = blockIdx.x;
  const int x = phys & 7, c = phys >> 3;          // XCD, chunk-local (0..63)
  const int gs = x * 2 + (c >> 5);                // global slice = bb*4+sp (0..15)
  const int qt = c & 31;
  const int bb = gs >> 2, sp = gs & 3;

  const int tid = threadIdx.x, lane = tid & 63, w = tid >> 6;
  const int ln32 = lane & 31, h = lane >> 5;
  const bool h0 = (h == 0);
  const int n0w = qt * 128 + w * 32;

  const bf16* qb = qkvt + (size_t)bb * 4096 * 768;
  const bf16* vb = vT + (size_t)bb * 256 * 4096;

  __shared__ bf16 KT[2][32 * 256];   // row=kv(32), 32 granules/row, swz: g ^= row
  __shared__ bf16 VT2[2][256 * 32];  // row=c(256), 4 granules/row, rot: g' = (g+(row>>1))&3

  // Q fragments (B-operand of S^T mfma): 32 q-rows x 256 ch, 16 ch-steps
  bf16x8 aq[16];
  #pragma unroll
  for (int step = 0; step < 16; ++step)
    aq[step] = ld8(qb + (size_t)(n0w + ln32) * 768 + step * 16 + h * 8);

  f32x16 acc[8] = {};
  float m_run = -3.0e38f, lsum = 0.f;

  // ---- prologue: stage tile 0 ----
  {
    int m0 = sp * 1024;
    #pragma unroll
    for (int i = 0; i < 4; ++i) {
      int G = i * 256 + tid;
      int kr = G >> 5, kc = G & 31;
      gload_lds16(qb + (size_t)(m0 + kr) * 768 + 256 + ((kc ^ kr) << 3), KT[0] + (size_t)G * 8);
      int vr = G >> 2, s = G & 3;
      int gsrc = (s + 4 - (vr >> 1)) & 3;
      gload_lds16(vb + (size_t)vr * 4096 + m0 + (gsrc << 3), VT2[0] + (size_t)G * 8);
    }
  }
  __syncthreads();

  int cur = 0;
  for (int t = 0; t < 32; ++t) {
    // ---- issue stage of next tile (overlaps with this tile's compute) ----
    if (t < 31) {
      int m0n = sp * 1024 + (t + 1) * 32;
      #pragma unroll
      for (int i = 0; i < 4; ++i) {
        int G = i * 256 + tid;
        int kr = G >> 5, kc = G & 31;
        gload_lds16(qb + (size_t)(m0n + kr) * 768 + 256 + ((kc ^ kr) << 3), KT[cur ^ 1] + (size_t)G * 8);
        int vr = G >> 2, s = G & 3;
        int gsrc = (s + 4 - (vr >> 1)) & 3;
        gload_lds16(vb + (size_t)vr * 4096 + m0n + (gsrc << 3), VT2[cur ^ 1] + (size_t)G * 8);
      }
    }

    const char* Kb = (const char*)KT[cur];
    const char* Vb = (const char*)VT2[cur];

    // ---- S^T = K . Q^T : lane holds P-row q=ln32, kv = (r&3)+8*(r>>2)+4h ----
    f32x16 s0 = {};
    __builtin_amdgcn_s_setprio(1);
    #pragma unroll
    for (int step = 0; step < 16; ++step) {
      bf16x8 k0 = *(const bf16x8*)(Kb + ln32 * 512 + (((step * 2 + h) ^ ln32) << 4));
      s0 = MFMA32(k0, aq[step], s0);
    }
    __builtin_amdgcn_s_setprio(0);

    // ---- row max (q=ln32 lives at lanes {ln32, ln32+32}) ----
    float mx = -3.0e38f;
    #pragma unroll
    for (int r = 0; r < 16; ++r) mx = fmaxf(mx, s0[r]);
    mx = fmaxf(mx, __shfl_xor(mx, 32));

    // ---- defer-max rescale ----
    if (__any(mx > m_run + 8.f)) {
      float mnew = fmaxf(m_run, mx);
      float alpha = __expf(m_run - mnew);
      m_run = mnew;
      lsum *= alpha;
      #pragma unroll
      for (int r = 0; r < 16; ++r) {
        int qacc = (r & 3) + 8 * (r >> 2) + 4 * h;
        float ar = __shfl(alpha, qacc);
        #pragma unroll
        for (int ct = 0; ct < 8; ++ct) acc[ct][r] *= ar;
      }
    }

    // ---- P = exp(S - m); packs; cross-half swap ----
    u32 pk0[8], sw0[8];
    #pragma unroll
    for (int m = 0; m < 8; ++m) {
      float a0 = __expf(s0[2 * m] - m_run), b0 = __expf(s0[2 * m + 1] - m_run);
      lsum += a0 + b0;
      pk0[m] = ((u32)f2bu(b0) << 16) | f2bu(a0);
    }
    #pragma unroll
    for (int m = 0; m < 8; ++m) sw0[m] = __shfl_xor(pk0[m], 32);

    // ---- O += P V : A-frag rebuilt in-register per 16-kv step ----
    __builtin_amdgcn_s_setprio(1);
    #pragma unroll
    for (int st = 0; st < 2; ++st) {
      const int A0 = 4 * st, A1 = A0 + 2;
      union { bf16x8 v; u32 u[4]; } af;
      af.u[0] = h0 ? pk0[A0]     : sw0[A1];
      af.u[1] = h0 ? pk0[A0 + 1] : sw0[A1 + 1];
      af.u[2] = h0 ? sw0[A0]     : pk0[A1];
      af.u[3] = h0 ? sw0[A0 + 1] : pk0[A1 + 1];
      #pragma unroll
      for (int ct = 0; ct < 8; ++ct) {
        int vrow = ct * 32 + ln32;
        bf16x8 bv = *(const bf16x8*)(Vb + vrow * 64 + ((((st * 2 + h) + (vrow >> 1)) & 3) << 4));
        acc[ct] = MFMA32(af.v, bv, acc[ct]);
      }
    }
    __builtin_amdgcn_s_setprio(0);

    __syncthreads();   // drains vmcnt: publishes next tile, protects cur tile
    cur ^= 1;
  }

  // ---- epilogue ----
  float Lrow = lsum + __shfl_xor(lsum, 32);
  size_t rb = (size_t)sp * 16384 + (size_t)bb * 4096;
  if (lane < 32) {
    ml[(rb + n0w + lane) * 2]     = m_run;
    ml[(rb + n0w + lane) * 2 + 1] = Lrow;
  }
  bf16* ob = Opart + rb * 256;
  #pragma unroll
  for (int r = 0; r < 16; ++r) {
    int qacc = (r & 3) + 8 * (r >> 2) + 4 * h;
    int n = n0w + qacc;
    #pragma unroll
    for (int ct = 0; ct < 8; ++ct)
      ob[(size_t)n * 256 + ct * 32 + ln32] = __float2bfloat16(acc[ct][r]);
  }
}

// ---------------- K4b: combine split-KV partials -> ho[b][n][c] ----------------
__global__ __launch_bounds__(256) void combine_kernel(const bf16* __restrict__ Opart,
                                                      const float* __restrict__ ml,
                                                      bf16* __restrict__ ho) {
  int rowg = blockIdx.x * 32 + (threadIdx.x >> 3);   // b*4096 + n
  int cg = (threadIdx.x & 7) * 32;
  float msp[4]; float M = -3.0e38f;
  #pragma unroll
  for (int sp = 0; sp < 4; ++sp) {
    msp[sp] = ml[((size_t)sp * 16384 + rowg) * 2];
    M = fmaxf(M, msp[sp]);
  }
  float acc[32];
  #pragma unroll
  for (int j = 0; j < 32; ++j) acc[j] = 0.f;
  float Ltot = 0.f;
  #pragma unroll
  for (int sp = 0; sp < 4; ++sp) {
    float sc = __expf(msp[sp] - M);
    Ltot += ml[((size_t)sp * 16384 + rowg) * 2 + 1] * sc;
    const bf16* p = Opart + ((size_t)sp * 16384 + rowg) * 256 + cg;
    #pragma unroll
    for (int v = 0; v < 4; ++v) {
      bf16x8 u = ld8(p + v * 8);
      #pragma unroll
      for (int j = 0; j < 8; ++j) acc[v * 8 + j] += sc * b2f((u16)u[j]);
    }
  }
  float inv = 1.f / Ltot;
  bf16* o = ho + (size_t)rowg * 256 + cg;
  #pragma unroll
  for (int v = 0; v < 4; ++v) {
    alignas(16) u16 u[8];
    #pragma unroll
    for (int j = 0; j < 8; ++j) u[j] = f2bu(acc[v * 8 + j] * inv);
    *reinterpret_cast<uint4*>(o + v * 8) = *reinterpret_cast<uint4*>(u);
  }
}

// ---------------- K5: proj GEMM + residual ----------------
__global__ __launch_bounds__(256) void proj_gemm(const bf16* __restrict__ ho,
                                                 const bf16* __restrict__ wp,
                                                 const float* __restrict__ pb,
                                                 const float* __restrict__ x,
                                                 float* __restrict__ out) {
  int bid = blockIdx.x;
  int nt = bid & 31; int rest = bid >> 5;
  int ot = rest & 1; int bb = rest >> 1;
  int tid = threadIdx.x, lane = tid & 63, w = tid >> 6;
  int ln = lane & 15, hi = lane >> 4;
  int wr = w >> 1, wc = w & 1;
  int o_base = ot * 128 + wr * 64, n_base = nt * 128 + wc * 64;
  const bf16* hb = ho + (size_t)bb * 4096 * 256;

  f32x4 acc[4][4] = {};
  for (int cb = 0; cb < 8; ++cb) {
    int c0 = cb * 32 + hi * 8;
    bf16x8 af[4], bfr[4];
    #pragma unroll
    for (int i = 0; i < 4; ++i) af[i]  = ld8(wp + (size_t)(o_base + i * 16 + ln) * 256 + c0);
    #pragma unroll
    for (int j = 0; j < 4; ++j) bfr[j] = ld8(hb + (size_t)(n_base + j * 16 + ln) * 256 + c0);
    #pragma unroll
    for (int i = 0; i < 4; ++i)
      #pragma unroll
      for (int j = 0; j < 4; ++j)
        acc[i][j] = MFMA16(af[i], bfr[j], acc[i][j]);
  }

  const float* xb = x + (size_t)bb * 256 * 4096;
  float* ob = out + (size_t)bb * 256 * 4096;
  #pragma unroll
  for (int i = 0; i < 4; ++i)
    #pragma unroll
    for (int r = 0; r < 4; ++r) {
      int o = o_base + i * 16 + hi * 4 + r;
      float bias = pb[o];
      #pragma unroll
      for (int j = 0; j < 4; ++j) {
        int n = n_base + j * 16 + ln;
        size_t idx = (size_t)o * 4096 + n;
        ob[idx] = xb[idx] + bias + acc[i][j][r];
      }
    }
}

extern "C" void kernel_launch(void* const* d_in, const int* in_sizes, int n_in,
                              void* d_out, int out_size, void* d_ws, size_t ws_size,
                              hipStream_t stream) {
  const float* x   = (const float*)d_in[0];
  const float* gnw = (const float*)d_in[1];
  const float* gnb = (const float*)d_in[2];
  const float* qw  = (const float*)d_in[3];
  const float* qb  = (const float*)d_in[4];
  const float* pw  = (const float*)d_in[5];
  const float* pb  = (const float*)d_in[6];
  float* out = (float*)d_out;

  char* ws = (char*)d_ws;
  bf16* ht    = (bf16*)(ws);                               // [4][4096][256]    0..8 MB
  bf16* qkvt  = (bf16*)(ws + ((size_t)8 << 20));           // [4][4096][768]    8..32 MB
  bf16* vT    = (bf16*)(ws + ((size_t)32 << 20));          // [4][256][4096]   32..40 MB
  bf16* ho    = (bf16*)(ws + ((size_t)40 << 20));          // [4][4096][256]   40..48 MB
  bf16* wqb   = (bf16*)(ws + ((size_t)48 << 20));          // [768][256]
  bf16* wpb   = (bf16*)(ws + ((size_t)48 << 20) + 768 * 256 * 2);
  float* ml   = (float*)(ws + ((size_t)48 << 20) + ((size_t)1 << 19)); // [4][16384][2] f32
  bf16* Opart = (bf16*)(ws + ((size_t)49 << 20));          // [4][16384][256] bf16, 49..81 MB

  wconv_kernel<<<dim3(256), dim3(256), 0, stream>>>(qw, pw, wqb, wpb);
  gn_kernel<<<dim3(128), dim3(256), 0, stream>>>(x, gnw, gnb, ht);
  qkv_gemm<<<dim3(768), dim3(256), 0, stream>>>(ht, wqb, qb, qkvt);
  vtrans_kernel<<<dim3(1024), dim3(256), 0, stream>>>(qkvt, vT);
  attn_kernel<<<dim3(512), dim3(256), 0, stream>>>(qkvt, vT, Opart, ml);
  combine_kernel<<<dim3(512), dim3(256), 0, stream>>>(Opart, ml, ho);
  proj_gemm<<<dim3(256), dim3(256), 0, stream>>>(ho, wpb, pb, x, out);
}

// Round 6
// 247.627 us; speedup vs baseline: 2.7719x; 1.1006x over previous
//
#include <hip/hip_runtime.h>
#include <hip/hip_bf16.h>

#define DEVI __device__ __forceinline__

typedef short bf16x8 __attribute__((ext_vector_type(8)));
typedef float f32x4  __attribute__((ext_vector_type(4)));
typedef float f32x16 __attribute__((ext_vector_type(16)));
typedef unsigned short u16;
typedef unsigned int u32;

using bf16 = __hip_bfloat16;

DEVI bf16x8 ld8(const bf16* p) { return *reinterpret_cast<const bf16x8*>(p); }

DEVI u16 f2bu(float f) {
  union { bf16 h; u16 u; } c; c.h = __float2bfloat16(f); return c.u;
}
DEVI float b2f(u16 u) {
  union { float f; unsigned int i; } c; c.i = ((unsigned int)u) << 16; return c.f;
}

DEVI void gload_lds16(const bf16* g, bf16* l) {
  typedef const __attribute__((address_space(1))) char* gp_t;
  typedef __attribute__((address_space(3))) char* lp_t;
  __builtin_amdgcn_global_load_lds((gp_t)(const void*)g, (lp_t)(void*)l, 16, 0, 0);
}

#define MFMA16(a, b, c) __builtin_amdgcn_mfma_f32_16x16x32_bf16((a), (b), (c), 0, 0, 0)
#define MFMA32(a, b, c) __builtin_amdgcn_mfma_f32_32x32x16_bf16((a), (b), (c), 0, 0, 0)

// Sizes: B=4, C=256, N=4096 (64x64), 3C=768, groups=32 (8 ch each)

// ---------------- K0: weights fp32 -> bf16 ----------------
__global__ __launch_bounds__(256) void wconv_kernel(const float* __restrict__ wq,
                                                    const float* __restrict__ wp,
                                                    bf16* __restrict__ wqb,
                                                    bf16* __restrict__ wpb) {
  int tid = blockIdx.x * 256 + threadIdx.x;
  const bool isq = tid < 49152;
  float4 v = isq ? ((const float4*)wq)[tid] : ((const float4*)wp)[tid - 49152];
  alignas(8) bf16 o[4] = { __float2bfloat16(v.x), __float2bfloat16(v.y),
                           __float2bfloat16(v.z), __float2bfloat16(v.w) };
  uint2 pk = *reinterpret_cast<uint2*>(o);
  if (isq) ((uint2*)wqb)[tid] = pk;
  else     ((uint2*)wpb)[tid - 49152] = pk;
}

// ---------------- K1: GroupNorm -> ht[b][n][c] bf16 ----------------
__global__ __launch_bounds__(256) void gn_kernel(const float* __restrict__ x,
                                                 const float* __restrict__ gw,
                                                 const float* __restrict__ gb,
                                                 bf16* __restrict__ ht) {
  const int blk = blockIdx.x;            // b*32 + g
  const int bb = blk >> 5, g = blk & 31;
  const float* xg = x + (size_t)(bb * 256 + g * 8) * 4096;

  float s = 0.f, ss = 0.f;
  const float4* x4 = (const float4*)xg;
  for (int i = threadIdx.x; i < 8192; i += 256) {
    float4 v = x4[i];
    s  += v.x + v.y + v.z + v.w;
    ss += v.x * v.x + v.y * v.y + v.z * v.z + v.w * v.w;
  }
  #pragma unroll
  for (int off = 32; off; off >>= 1) {
    s  += __shfl_down(s, off);
    ss += __shfl_down(ss, off);
  }
  __shared__ float red[8];
  int wave = threadIdx.x >> 6;
  if ((threadIdx.x & 63) == 0) { red[wave * 2] = s; red[wave * 2 + 1] = ss; }
  __syncthreads();
  if (threadIdx.x == 0) {
    float S = red[0] + red[2] + red[4] + red[6];
    float SS = red[1] + red[3] + red[5] + red[7];
    float mu = S * (1.f / 32768.f);
    float var = SS * (1.f / 32768.f) - mu * mu;
    red[0] = mu; red[1] = rsqrtf(var + 1e-5f);
  }
  __syncthreads();
  const float mu = red[0], rstd = red[1];

  float gm[8], bt[8];
  #pragma unroll
  for (int j = 0; j < 8; ++j) {
    float wv = gw[g * 8 + j] * rstd;
    gm[j] = wv; bt[j] = gb[g * 8 + j] - mu * wv;
  }
  bf16* hrow = ht + (size_t)bb * 4096 * 256 + g * 8;
  for (int n = threadIdx.x; n < 4096; n += 256) {
    alignas(16) u16 u[8];
    #pragma unroll
    for (int j = 0; j < 8; ++j)
      u[j] = f2bu(xg[j * 4096 + n] * gm[j] + bt[j]);
    *reinterpret_cast<uint4*>(hrow + (size_t)n * 256) = *reinterpret_cast<uint4*>(u);
  }
}

// ---------------- K2: QKV GEMM (staged), qkvt[n][o] = ht[n][c]*W[o][c]^T + bias ----------------
// grid 768, 256 thr, 2 blocks/CU. 128x128 tile, BK=64, dbuf LDS 64KB.
// L = bb*192 + nt*6 + ot; XCD gets 96 consecutive L (A-tile sharers co-located).
__global__ __launch_bounds__(256, 2) void qkv_gemm(const bf16* __restrict__ ht,
                                                   const bf16* __restrict__ wq,
                                                   const float* __restrict__ qkvb,
                                                   bf16* __restrict__ qkvt) {
  const int phys = blockIdx.x;
  const int L = (phys & 7) * 96 + (phys >> 3);
  const int bb = L / 192; const int rem = L - bb * 192;
  const int nt = rem / 6, ot = rem - nt * 6;

  const int tid = threadIdx.x, lane = tid & 63, w = tid >> 6;
  const int ln = lane & 15, hi = lane >> 4;
  const int wr = w >> 1, wc = w & 1;
  const int n_base = nt * 128, o_base = ot * 128;
  const bf16* hb = ht + (size_t)bb * 4096 * 256;

  __shared__ bf16 At[2][128 * 64];   // row-major [128][64ch], slot swz: g ^= (row&7)
  __shared__ bf16 Bt[2][128 * 64];

  f32x4 acc[4][4] = {};

  // prologue: stage k-step 0
  {
    #pragma unroll
    for (int i = 0; i < 4; ++i) {
      int G = i * 256 + tid; int row = G >> 3, g = G & 7;
      int cofs = (g ^ (row & 7)) << 3;
      gload_lds16(hb + (size_t)(n_base + row) * 256 + cofs, At[0] + (size_t)G * 8);
      gload_lds16(wq + (size_t)(o_base + row) * 256 + cofs, Bt[0] + (size_t)G * 8);
    }
  }
  __syncthreads();

  int cur = 0;
  for (int ks = 0; ks < 4; ++ks) {
    if (ks < 3) {
      int k0 = (ks + 1) * 64;
      #pragma unroll
      for (int i = 0; i < 4; ++i) {
        int G = i * 256 + tid; int row = G >> 3, g = G & 7;
        int cofs = k0 + ((g ^ (row & 7)) << 3);
        gload_lds16(hb + (size_t)(n_base + row) * 256 + cofs, At[cur ^ 1] + (size_t)G * 8);
        gload_lds16(wq + (size_t)(o_base + row) * 256 + cofs, Bt[cur ^ 1] + (size_t)G * 8);
      }
    }
    const char* Ab = (const char*)At[cur];
    const char* Bb = (const char*)Bt[cur];
    __builtin_amdgcn_s_setprio(1);
    #pragma unroll
    for (int cb = 0; cb < 2; ++cb) {
      bf16x8 af[4], bfr[4];
      #pragma unroll
      for (int i = 0; i < 4; ++i) {
        int row = wr * 64 + i * 16 + ln;
        af[i] = *(const bf16x8*)(Ab + row * 128 + (((cb * 4 + hi) ^ (row & 7)) << 4));
      }
      #pragma unroll
      for (int j = 0; j < 4; ++j) {
        int row = wc * 64 + j * 16 + ln;
        bfr[j] = *(const bf16x8*)(Bb + row * 128 + (((cb * 4 + hi) ^ (row & 7)) << 4));
      }
      #pragma unroll
      for (int i = 0; i < 4; ++i)
        #pragma unroll
        for (int j = 0; j < 4; ++j)
          acc[i][j] = MFMA16(af[i], bfr[j], acc[i][j]);
    }
    __builtin_amdgcn_s_setprio(0);
    __syncthreads();
    cur ^= 1;
  }

  const float sc = (ot < 2) ? 0.0625f : 1.0f;   // fold 1/sqrt(C)=1/16 into Q
  bf16* ob = qkvt + (size_t)bb * 4096 * 768;
  #pragma unroll
  for (int j = 0; j < 4; ++j) {
    int o = o_base + wc * 64 + j * 16 + ln;
    float bias = qkvb[o];
    #pragma unroll
    for (int i = 0; i < 4; ++i)
      #pragma unroll
      for (int r = 0; r < 4; ++r) {
        int n = n_base + wr * 64 + i * 16 + hi * 4 + r;
        ob[(size_t)n * 768 + o] = __float2bfloat16((acc[i][j][r] + bias) * sc);
      }
  }
}

// ---------------- K3: transpose V -> vT[c][n] ----------------
__global__ __launch_bounds__(256) void vtrans_kernel(const bf16* __restrict__ qkvt,
                                                     bf16* __restrict__ vT) {
  int bid = blockIdx.x;
  int ct = bid & 3, ntile = (bid >> 2) & 63, bb = bid >> 8;
  __shared__ bf16 T[64][72];
  int tid = threadIdx.x;
  int i = tid >> 3, j8 = (tid & 7) * 8;
  const bf16* src = qkvt + (size_t)bb * 4096 * 768 + (size_t)(ntile * 64 + i) * 768 + 512 + ct * 64 + j8;
  #pragma unroll
  for (int p = 0; p < 2; ++p) {
    bf16x8 v = ld8(src + (size_t)p * 32 * 768);
    *reinterpret_cast<bf16x8*>(&T[i + p * 32][j8]) = v;
  }
  __syncthreads();
  bf16* dst = vT + (size_t)bb * 256 * 4096 + (size_t)(ct * 64) * 4096 + ntile * 64;
  #pragma unroll
  for (int p = 0; p < 2; ++p) {
    int c = i + p * 32;
    alignas(16) bf16 u[8];
    #pragma unroll
    for (int q = 0; q < 8; ++q) u[q] = T[j8 + q][c];
    *reinterpret_cast<uint4*>(dst + (size_t)c * 4096 + j8) = *reinterpret_cast<uint4*>(u);
  }
}

// ---------------- K4: flash attention, 32x32 MFMA, swapped QK^T, in-register P ----------------
// grid 512, 256 threads (4 waves x 32 q-rows = 128 q-rows/block), 2 blocks/CU.
// KV tile 32: K[32][256] (16KB) + V^T[256][32] (16KB), double-buffered = 64KB LDS.
// XCD-aligned: each XCD hosts exactly 2 (bb,sp) KV slices (2MB < 4MB L2).
__global__ __launch_bounds__(256, 2) void attn_kernel(const bf16* __restrict__ qkvt,
                                                      const bf16* __restrict__ vT,
                                                      bf16* __restrict__ Opart,
                                                      float* __restrict__ ml) {
  const int phys = blockIdx.x;
  const int x = phys & 7, c = phys >> 3;          // XCD, chunk-local (0..63)
  const int gs = x * 2 + (c >> 5);                // global slice = bb*4+sp (0..15)
  const int qt = c & 31;
  const int bb = gs >> 2, sp = gs & 3;

  const int tid = threadIdx.x, lane = tid & 63, w = tid >> 6;
  const int ln32 = lane & 31, h = lane >> 5;
  const bool h0 = (h == 0);
  const int n0w = qt * 128 + w * 32;

  const bf16* qb = qkvt + (size_t)bb * 4096 * 768;
  const bf16* vb = vT + (size_t)bb * 256 * 4096;

  __shared__ bf16 KT[2][32 * 256];   // row=kv(32), 32 granules/row, swz: g ^= row
  __shared__ bf16 VT2[2][256 * 32];  // row=c(256), 4 granules/row, rot: g' = (g+(row>>1))&3

  // Q fragments (B-operand of S^T mfma): 32 q-rows x 256 ch, 16 ch-steps
  bf16x8 aq[16];
  #pragma unroll
  for (int step = 0; step < 16; ++step)
    aq[step] = ld8(qb + (size_t)(n0w + ln32) * 768 + step * 16 + h * 8);

  f32x16 acc[8] = {};
  float m_run = -3.0e38f, lsum = 0.f;

  // ---- prologue: stage tile 0 ----
  {
    int m0 = sp * 1024;
    #pragma unroll
    for (int i = 0; i < 4; ++i) {
      int G = i * 256 + tid;
      int kr = G >> 5, kc = G & 31;
      gload_lds16(qb + (size_t)(m0 + kr) * 768 + 256 + ((kc ^ kr) << 3), KT[0] + (size_t)G * 8);
      int vr = G >> 2, s = G & 3;
      int gsrc = (s + 4 - (vr >> 1)) & 3;
      gload_lds16(vb + (size_t)vr * 4096 + m0 + (gsrc << 3), VT2[0] + (size_t)G * 8);
    }
  }
  __syncthreads();

  int cur = 0;
  for (int t = 0; t < 32; ++t) {
    // ---- issue stage of next tile (overlaps with this tile's compute) ----
    if (t < 31) {
      int m0n = sp * 1024 + (t + 1) * 32;
      #pragma unroll
      for (int i = 0; i < 4; ++i) {
        int G = i * 256 + tid;
        int kr = G >> 5, kc = G & 31;
        gload_lds16(qb + (size_t)(m0n + kr) * 768 + 256 + ((kc ^ kr) << 3), KT[cur ^ 1] + (size_t)G * 8);
        int vr = G >> 2, s = G & 3;
        int gsrc = (s + 4 - (vr >> 1)) & 3;
        gload_lds16(vb + (size_t)vr * 4096 + m0n + (gsrc << 3), VT2[cur ^ 1] + (size_t)G * 8);
      }
    }

    const char* Kb = (const char*)KT[cur];
    const char* Vb = (const char*)VT2[cur];

    // ---- S^T = K . Q^T : lane holds P-row q=ln32, kv = (r&3)+8*(r>>2)+4h ----
    f32x16 s0 = {};
    __builtin_amdgcn_s_setprio(1);
    #pragma unroll
    for (int step = 0; step < 16; ++step) {
      bf16x8 k0 = *(const bf16x8*)(Kb + ln32 * 512 + (((step * 2 + h) ^ ln32) << 4));
      s0 = MFMA32(k0, aq[step], s0);
    }
    __builtin_amdgcn_s_setprio(0);

    // ---- row max (q=ln32 lives at lanes {ln32, ln32+32}) ----
    float mx = -3.0e38f;
    #pragma unroll
    for (int r = 0; r < 16; ++r) mx = fmaxf(mx, s0[r]);
    mx = fmaxf(mx, __shfl_xor(mx, 32));

    // ---- defer-max rescale ----
    if (__any(mx > m_run + 8.f)) {
      float mnew = fmaxf(m_run, mx);
      float alpha = __expf(m_run - mnew);
      m_run = mnew;
      lsum *= alpha;
      #pragma unroll
      for (int r = 0; r < 16; ++r) {
        int qacc = (r & 3) + 8 * (r >> 2) + 4 * h;
        float ar = __shfl(alpha, qacc);
        #pragma unroll
        for (int ct = 0; ct < 8; ++ct) acc[ct][r] *= ar;
      }
    }

    // ---- P = exp(S - m); packs; cross-half swap ----
    u32 pk0[8], sw0[8];
    #pragma unroll
    for (int m = 0; m < 8; ++m) {
      float a0 = __expf(s0[2 * m] - m_run), b0 = __expf(s0[2 * m + 1] - m_run);
      lsum += a0 + b0;
      pk0[m] = ((u32)f2bu(b0) << 16) | f2bu(a0);
    }
    #pragma unroll
    for (int m = 0; m < 8; ++m) sw0[m] = __shfl_xor(pk0[m], 32);

    // ---- O += P V : A-frag rebuilt in-register per 16-kv step ----
    __builtin_amdgcn_s_setprio(1);
    #pragma unroll
    for (int st = 0; st < 2; ++st) {
      const int A0 = 4 * st, A1 = A0 + 2;
      union { bf16x8 v; u32 u[4]; } af;
      af.u[0] = h0 ? pk0[A0]     : sw0[A1];
      af.u[1] = h0 ? pk0[A0 + 1] : sw0[A1 + 1];
      af.u[2] = h0 ? sw0[A0]     : pk0[A1];
      af.u[3] = h0 ? sw0[A0 + 1] : pk0[A1 + 1];
      #pragma unroll
      for (int ct = 0; ct < 8; ++ct) {
        int vrow = ct * 32 + ln32;
        bf16x8 bv = *(const bf16x8*)(Vb + vrow * 64 + ((((st * 2 + h) + (vrow >> 1)) & 3) << 4));
        acc[ct] = MFMA32(af.v, bv, acc[ct]);
      }
    }
    __builtin_amdgcn_s_setprio(0);

    __syncthreads();   // drains vmcnt: publishes next tile, protects cur tile
    cur ^= 1;
  }

  // ---- epilogue ----
  float Lrow = lsum + __shfl_xor(lsum, 32);
  size_t rb = (size_t)sp * 16384 + (size_t)bb * 4096;
  if (lane < 32) {
    ml[(rb + n0w + lane) * 2]     = m_run;
    ml[(rb + n0w + lane) * 2 + 1] = Lrow;
  }
  bf16* ob = Opart + rb * 256;
  #pragma unroll
  for (int r = 0; r < 16; ++r) {
    int qacc = (r & 3) + 8 * (r >> 2) + 4 * h;
    int n = n0w + qacc;
    #pragma unroll
    for (int ct = 0; ct < 8; ++ct)
      ob[(size_t)n * 256 + ct * 32 + ln32] = __float2bfloat16(acc[ct][r]);
  }
}

// ---------------- K4b: combine split-KV partials -> ho[b][n][c] ----------------
__global__ __launch_bounds__(256) void combine_kernel(const bf16* __restrict__ Opart,
                                                      const float* __restrict__ ml,
                                                      bf16* __restrict__ ho) {
  int rowg = blockIdx.x * 32 + (threadIdx.x >> 3);   // b*4096 + n
  int cg = (threadIdx.x & 7) * 32;
  float msp[4]; float M = -3.0e38f;
  #pragma unroll
  for (int sp = 0; sp < 4; ++sp) {
    msp[sp] = ml[((size_t)sp * 16384 + rowg) * 2];
    M = fmaxf(M, msp[sp]);
  }
  float acc[32];
  #pragma unroll
  for (int j = 0; j < 32; ++j) acc[j] = 0.f;
  float Ltot = 0.f;
  #pragma unroll
  for (int sp = 0; sp < 4; ++sp) {
    float sc = __expf(msp[sp] - M);
    Ltot += ml[((size_t)sp * 16384 + rowg) * 2 + 1] * sc;
    const bf16* p = Opart + ((size_t)sp * 16384 + rowg) * 256 + cg;
    #pragma unroll
    for (int v = 0; v < 4; ++v) {
      bf16x8 u = ld8(p + v * 8);
      #pragma unroll
      for (int j = 0; j < 8; ++j) acc[v * 8 + j] += sc * b2f((u16)u[j]);
    }
  }
  float inv = 1.f / Ltot;
  bf16* o = ho + (size_t)rowg * 256 + cg;
  #pragma unroll
  for (int v = 0; v < 4; ++v) {
    alignas(16) u16 u[8];
    #pragma unroll
    for (int j = 0; j < 8; ++j) u[j] = f2bu(acc[v * 8 + j] * inv);
    *reinterpret_cast<uint4*>(o + v * 8) = *reinterpret_cast<uint4*>(u);
  }
}

// ---------------- K5: proj GEMM (staged) + residual ----------------
// grid 256, 256 thr. 128x128 tile (o x n), BK=64, dbuf LDS 64KB.
__global__ __launch_bounds__(256, 2) void proj_gemm(const bf16* __restrict__ ho,
                                                    const bf16* __restrict__ wp,
                                                    const float* __restrict__ pb,
                                                    const float* __restrict__ x,
                                                    float* __restrict__ out) {
  const int phys = blockIdx.x;
  const int L = (phys & 7) * 32 + (phys >> 3);
  const int bb = L >> 6; const int rem = L & 63;
  const int ot = rem >> 5, nt = rem & 31;

  const int tid = threadIdx.x, lane = tid & 63, w = tid >> 6;
  const int ln = lane & 15, hi = lane >> 4;
  const int wr = w >> 1, wc = w & 1;
  const int o_base = ot * 128, n_base = nt * 128;
  const bf16* hb = ho + (size_t)bb * 4096 * 256;

  __shared__ bf16 Wt[2][128 * 64];
  __shared__ bf16 Ht[2][128 * 64];

  f32x4 acc[4][4] = {};

  {
    #pragma unroll
    for (int i = 0; i < 4; ++i) {
      int G = i * 256 + tid; int row = G >> 3, g = G & 7;
      int cofs = (g ^ (row & 7)) << 3;
      gload_lds16(wp + (size_t)(o_base + row) * 256 + cofs, Wt[0] + (size_t)G * 8);
      gload_lds16(hb + (size_t)(n_base + row) * 256 + cofs, Ht[0] + (size_t)G * 8);
    }
  }
  __syncthreads();

  int cur = 0;
  for (int ks = 0; ks < 4; ++ks) {
    if (ks < 3) {
      int k0 = (ks + 1) * 64;
      #pragma unroll
      for (int i = 0; i < 4; ++i) {
        int G = i * 256 + tid; int row = G >> 3, g = G & 7;
        int cofs = k0 + ((g ^ (row & 7)) << 3);
        gload_lds16(wp + (size_t)(o_base + row) * 256 + cofs, Wt[cur ^ 1] + (size_t)G * 8);
        gload_lds16(hb + (size_t)(n_base + row) * 256 + cofs, Ht[cur ^ 1] + (size_t)G * 8);
      }
    }
    const char* Ab = (const char*)Wt[cur];
    const char* Bb = (const char*)Ht[cur];
    __builtin_amdgcn_s_setprio(1);
    #pragma unroll
    for (int cb = 0; cb < 2; ++cb) {
      bf16x8 af[4], bfr[4];
      #pragma unroll
      for (int i = 0; i < 4; ++i) {
        int row = wr * 64 + i * 16 + ln;
        af[i] = *(const bf16x8*)(Ab + row * 128 + (((cb * 4 + hi) ^ (row & 7)) << 4));
      }
      #pragma unroll
      for (int j = 0; j < 4; ++j) {
        int row = wc * 64 + j * 16 + ln;
        bfr[j] = *(const bf16x8*)(Bb + row * 128 + (((cb * 4 + hi) ^ (row & 7)) << 4));
      }
      #pragma unroll
      for (int i = 0; i < 4; ++i)
        #pragma unroll
        for (int j = 0; j < 4; ++j)
          acc[i][j] = MFMA16(af[i], bfr[j], acc[i][j]);
    }
    __builtin_amdgcn_s_setprio(0);
    __syncthreads();
    cur ^= 1;
  }

  const float* xb = x + (size_t)bb * 256 * 4096;
  float* ob = out + (size_t)bb * 256 * 4096;
  #pragma unroll
  for (int i = 0; i < 4; ++i)
    #pragma unroll
    for (int r = 0; r < 4; ++r) {
      int o = o_base + wr * 64 + i * 16 + hi * 4 + r;
      float bias = pb[o];
      #pragma unroll
      for (int j = 0; j < 4; ++j) {
        int n = n_base + wc * 64 + j * 16 + ln;
        size_t idx = (size_t)o * 4096 + n;
        ob[idx] = xb[idx] + bias + acc[i][j][r];
      }
    }
}

extern "C" void kernel_launch(void* const* d_in, const int* in_sizes, int n_in,
                              void* d_out, int out_size, void* d_ws, size_t ws_size,
                              hipStream_t stream) {
  const float* x   = (const float*)d_in[0];
  const float* gnw = (const float*)d_in[1];
  const float* gnb = (const float*)d_in[2];
  const float* qw  = (const float*)d_in[3];
  const float* qb  = (const float*)d_in[4];
  const float* pw  = (const float*)d_in[5];
  const float* pb  = (const float*)d_in[6];
  float* out = (float*)d_out;

  char* ws = (char*)d_ws;
  bf16* ht    = (bf16*)(ws);                               // [4][4096][256]    0..8 MB
  bf16* qkvt  = (bf16*)(ws + ((size_t)8 << 20));           // [4][4096][768]    8..32 MB
  bf16* vT    = (bf16*)(ws + ((size_t)32 << 20));          // [4][256][4096]   32..40 MB
  bf16* ho    = (bf16*)(ws + ((size_t)40 << 20));          // [4][4096][256]   40..48 MB
  bf16* wqb   = (bf16*)(ws + ((size_t)48 << 20));          // [768][256]
  bf16* wpb   = (bf16*)(ws + ((size_t)48 << 20) + 768 * 256 * 2);
  float* ml   = (float*)(ws + ((size_t)48 << 20) + ((size_t)1 << 19)); // [4][16384][2] f32
  bf16* Opart = (bf16*)(ws + ((size_t)49 << 20));          // [4][16384][256] bf16, 49..81 MB

  wconv_kernel<<<dim3(256), dim3(256), 0, stream>>>(qw, pw, wqb, wpb);
  gn_kernel<<<dim3(128), dim3(256), 0, stream>>>(x, gnw, gnb, ht);
  qkv_gemm<<<dim3(768), dim3(256), 0, stream>>>(ht, wqb, qb, qkvt);
  vtrans_kernel<<<dim3(1024), dim3(256), 0, stream>>>(qkvt, vT);
  attn_kernel<<<dim3(512), dim3(256), 0, stream>>>(qkvt, vT, Opart, ml);
  combine_kernel<<<dim3(512), dim3(256), 0, stream>>>(Opart, ml, ho);
  proj_gemm<<<dim3(256), dim3(256), 0, stream>>>(ho, wpb, pb, x, out);
}